// Round 12
// baseline (355.094 us; speedup 1.0000x reference)
//
#include <hip/hip_runtime.h>
#include <cstdint>
#include <cstddef>

typedef _Float16 f16;
typedef _Float16 f16x2 __attribute__((ext_vector_type(2)));
typedef _Float16 f16x8 __attribute__((ext_vector_type(8)));
typedef float    f32x4 __attribute__((ext_vector_type(4)));

// ---------------- problem constants ----------------
constexpr int NTOKC  = 197;
constexpr int TTOK   = 128 * 197;         // 25216
constexpr int EMB    = 384;
constexpr int HID    = 1536;

// ---------------- workspace layout (bytes) ----------------
constexpr size_t OFF_CONVW   = 0;                        // 384*768 f16
constexpr size_t OFF_EW1T    = 1179648;                  // 4*1536*384 f16
constexpr size_t OFF_EW2T    = 5898240;                  // 4*384*1536 f16
constexpr size_t OFF_HEADW16 = 10616832;                 // 1024*384 f16
constexpr size_t OFF_XCLS16  = 11403264;                 // 384 f16
constexpr size_t OFF_HCLS16  = 11799552;                 // 128*384 f16
constexpr size_t OFF_MASKW   = 11897856;                 // 128*4 f32
constexpr size_t OFF_EH      = 11899904;                 // 4*128*1536 f16
constexpr size_t OFF_EPART   = 13472768;                 // 4kc*4e*128*384 f32
constexpr size_t OFF_HFIN    = 16618496;                 // 128*384 f16
constexpr size_t OFF_XH      = 16716800;                 // TTOK*384 f16
constexpr size_t OFF_R       = 36082688;                 // 6*384 f32
constexpr size_t OFF_CVEC    = 36094976;                 // 6 f32
constexpr size_t OFF_U16     = 36099072;                 // 128*2304 f16
constexpr size_t OFF_SG      = 38212608;                 // 128*6*197 f32
constexpr size_t OFF_SCLS    = 38817792;                 // 6 f32
constexpr size_t OFF_F       = 38818816;                 // 384*2304 f16
constexpr size_t OFF_B2      = 40588288;                 // 384 f32
constexpr size_t OFF_FPART   = 40589824;                 // 6kc*128*384 f32
constexpr size_t WS_NEEDED   = 41769472;                 // ~41.8 MB

// ---------------- global_load_lds helper ----------------
__device__ __forceinline__ void gload16(const void* g, void* l) {
  __builtin_amdgcn_global_load_lds(
      (__attribute__((address_space(1))) void*)(void*)g,
      (__attribute__((address_space(3))) void*)l, 16, 0, 0);
}

#define PACK8(hv, p0, p1) { hv[0]=(f16)p0.x; hv[1]=(f16)p0.y; hv[2]=(f16)p0.z; hv[3]=(f16)p0.w; \
                            hv[4]=(f16)p1.x; hv[5]=(f16)p1.y; hv[6]=(f16)p1.z; hv[7]=(f16)p1.w; }

// ---------------- ALL weight prep in ONE launch --------------------------------
// bx ranges: [0,2688) casts | [2688,4992) ew1 transpose | [4992,7296) ew2 transpose
//            [7296,7440) Wfused | [7440,7464) bias2
__global__ __launch_bounds__(256) void prep_all_k(
    const float* __restrict__ conv_w, const float* __restrict__ head_w,
    const float* __restrict__ ew1, const float* __restrict__ ew2,
    const float* __restrict__ inp_w, const float* __restrict__ inp_b,
    const float* __restrict__ outp_w, const float* __restrict__ outp_b,
    f16* __restrict__ convw, f16* __restrict__ headw16,
    f16* __restrict__ ew1t, f16* __restrict__ ew2t,
    f16* __restrict__ F, float* __restrict__ bias2) {
  __shared__ __attribute__((aligned(16))) char sbuf[4352];
  const int bx = (int)blockIdx.x, tid = threadIdx.x;
  if (bx < 2688) {
    int i = bx * 256 + tid;
    if (i < 294912) convw[i] = (f16)conv_w[i];
    int j = i - 294912;
    if (j >= 0 && j < 393216) {
      int row = j / 384;
      headw16[j] = (row < 1000) ? (f16)head_w[j] : (f16)0.f;
    }
  } else if (bx < 4992) {
    float (*tile)[33] = (float(*)[33])sbuf;
    int local = bx - 2688;
    int e = local / 576, r2 = local - e * 576;
    int byy = r2 / 48, bxx = r2 - byy * 48;
    const float* pin = ew1 + (size_t)e * 384 * 1536;
    f16* pout = ew1t + (size_t)e * 384 * 1536;
    int c0 = bxx * 32, r0 = byy * 32;
    int tx = tid & 31, ty = tid >> 5;
#pragma unroll
    for (int i = 0; i < 4; i++)
      tile[ty + 8 * i][tx] = pin[(size_t)(r0 + ty + 8 * i) * 1536 + c0 + tx];
    __syncthreads();
#pragma unroll
    for (int i = 0; i < 4; i++)
      pout[(size_t)(c0 + ty + 8 * i) * 384 + r0 + tx] = (f16)tile[tx][ty + 8 * i];
  } else if (bx < 7296) {
    float (*tile)[33] = (float(*)[33])sbuf;
    int local = bx - 4992;
    int e = local / 576, r2 = local - e * 576;
    int byy = r2 / 12, bxx = r2 - byy * 12;
    const float* pin = ew2 + (size_t)e * 1536 * 384;
    f16* pout = ew2t + (size_t)e * 1536 * 384;
    int c0 = bxx * 32, r0 = byy * 32;
    int tx = tid & 31, ty = tid >> 5;
#pragma unroll
    for (int i = 0; i < 4; i++)
      tile[ty + 8 * i][tx] = pin[(size_t)(r0 + ty + 8 * i) * 384 + c0 + tx];
    __syncthreads();
#pragma unroll
    for (int i = 0; i < 4; i++)
      pout[(size_t)(c0 + ty + 8 * i) * 1536 + r0 + tx] = (f16)tile[tx][ty + 8 * i];
  } else if (bx < 7440) {
    // F[n][h*384+k] = sum_d Wout[n][h*64+d] * Wv[h*64+d][k]
    float (*wo)[64] = (float(*)[64])sbuf;   // [16][64]
    int local = bx - 7296;
    int h = local / 24, nt = local - h * 24;
    int n0 = nt * 16;
    for (int i = tid; i < 1024; i += 256) {
      int ni = i >> 6, d = i & 63;
      wo[ni][d] = outp_w[(size_t)(n0 + ni) * 384 + h * 64 + d];
    }
    __syncthreads();
    for (int e = tid; e < 6144; e += 256) {
      int ni = e / 384, k2 = e - ni * 384;
      const float* wv = inp_w + (size_t)(768 + h * 64) * 384 + k2;
      float a = 0.f;
#pragma unroll 8
      for (int d = 0; d < 64; d++) a += wo[ni][d] * wv[(size_t)d * 384];
      F[(size_t)(n0 + ni) * 2304 + h * 384 + k2] = (f16)a;
    }
  } else {
    // bias2[n] = bout[n] + sum_c Wout[n][c]*bv[c]
    int nt = bx - 7440;
    if (tid < 16) {
      int n = nt * 16 + tid;
      const float* wrow = outp_w + (size_t)n * 384;
      float a = outp_b[n];
      for (int c = 0; c < 384; c++) a += wrow[c] * inp_b[768 + c];
      bias2[n] = a;
    }
  }
}

// ---------------- cls LN + q_h + r_h + c_h + Scls_h (one launch, 6 blocks) -----
__global__ __launch_bounds__(384) void clsrprep_k(
    const float* __restrict__ cls, const float* __restrict__ posw,
    const float* __restrict__ g, const float* __restrict__ bb,
    const float* __restrict__ inp_w, const float* __restrict__ inp_b,
    f16* __restrict__ xcls16, float* __restrict__ Rg,
    float* __restrict__ Cg, float* __restrict__ Scls) {
  __shared__ float xs[EMB];
  __shared__ float red[16];
  __shared__ float qh[64];
  __shared__ float sred[6];
  const int h = (int)blockIdx.x, t = threadIdx.x;
  const int lane = t & 63, wave = t >> 6;
  float v = cls[t] + posw[t];
  float s = v, sq = v * v;
#pragma unroll
  for (int off = 32; off; off >>= 1) {
    s += __shfl_xor(s, off);
    sq += __shfl_xor(sq, off);
  }
  if (lane == 0) { red[wave] = s; red[8 + wave] = sq; }
  __syncthreads();
  float S = 0.f, SQ = 0.f;
#pragma unroll
  for (int i = 0; i < 6; i++) { S += red[i]; SQ += red[8 + i]; }
  float m = S * (1.f / 384.f);
  float rs = rsqrtf(SQ * (1.f / 384.f) - m * m + 1e-5f);
  float y = (v - m) * rs * g[t] + bb[t];
  xs[t] = y;
  xcls16[t] = (f16)y;      // redundant identical writes across blocks: benign
  __syncthreads();
  if (t < 64) {
    const float* wq = inp_w + (size_t)(h * 64 + t) * 384;
    float a = inp_b[h * 64 + t];
#pragma unroll 8
    for (int c = 0; c < 384; c++) a += wq[c] * xs[c];
    qh[t] = a;
  }
  __syncthreads();
  const float* wp = inp_w + (size_t)(384 + h * 64) * 384 + t;
  float a = 0.f;
#pragma unroll 8
  for (int d = 0; d < 64; d++) a += wp[(size_t)d * 384] * qh[d];
  Rg[h * 384 + t] = a;
  float part = a * xs[t];
#pragma unroll
  for (int off = 32; off; off >>= 1) part += __shfl_xor(part, off);
  if (lane == 0) sred[wave] = part;
  __syncthreads();
  if (t == 0) {
    float c = 0.f;
    for (int d = 0; d < 64; d++) c += qh[d] * inp_b[384 + h * 64 + d];
    Cg[h] = c;
    float st = c;
#pragma unroll
    for (int i = 0; i < 6; i++) st += sred[i];
    Scls[h] = st;
  }
}

// ---------------- fused implicit-im2col embed GEMM + LN1 + score epilogue ------
// dbuf K-loop with COUNTED vmcnt across raw barriers (no per-iter vmcnt(0) drain).
__global__ __launch_bounds__(1024) void embed_ln_k(
    const float* __restrict__ img, const f16* __restrict__ B,
    const float* __restrict__ bias, const float* __restrict__ posw,
    const float* __restrict__ g, const float* __restrict__ bb,
    const float* __restrict__ Rg, const float* __restrict__ Cg,
    const f16* __restrict__ xcls16, const float* __restrict__ Scls,
    f16* __restrict__ xh, float* __restrict__ Sg) {
  __shared__ __attribute__((aligned(16))) char smem[57344];
  f16* As0 = (f16*)smem;
  f16* As1 = (f16*)(smem + 4096);
  f16* Bs0 = (f16*)(smem + 8192);
  f16* Bs1 = (f16*)(smem + 32768);
  const int K = 768;
  const int NT = 24;
  const int tid = threadIdx.x;
  const int lane = tid & 63;
  const int wave = tid >> 6;
  const int rowgrp = wave & 3;
  const int colgrp = wave >> 2;
  const int m0 = (int)blockIdx.x * 64;
  const int fr = lane & 15;
  const int fq = lane >> 4;

  // folded cls broadcast
  if (blockIdx.x < 128) {
    if (tid < 384) xh[(size_t)blockIdx.x * NTOKC * EMB + tid] = xcls16[tid];
    if (tid < 6) Sg[((size_t)blockIdx.x * 6 + tid) * 197] = Scls[tid];
  }

  f32x4 acc[6];
#pragma unroll
  for (int j = 0; j < 6; j++) acc[j] = f32x4{0.f, 0.f, 0.f, 0.f};

  const int sr = lane >> 2, sc = (lane & 3) * 8;
  const int swzS = (((lane & 3) ^ (sr & 3)) * 8);   // staging swizzled chunk (halfwords)
  const int swzR = ((fq ^ (fr & 3)) * 8);           // read swizzled chunk

  const float* abase = nullptr;
  int adoff = 0;
  if (wave < 4) {
    int row = m0 + wave * 16 + sr;
    int bimg = row / 196;
    int pp = row - bimg * 196;
    int py = pp / 14, px = pp - py * 14;
    int kx0 = sc & 15;
    abase = img + ((size_t)(bimg * 3) * 224 + py * 16) * 224 + px * 16 + kx0;
    adoff = (wave * 16 + sr) * 32 + swzS;           // swizzled LDS dest
  }
  const f16* gb0 = nullptr;
  int lboff = 0;
  if (wave >= 4) {
    int brow = (wave - 4) * 32;
    gb0 = B + (size_t)(brow + sr) * K + swzS;       // pre-swizzled GLOBAL source
    lboff = brow * 32;                              // linear LDS dest
  }

  // prologue: stage tile0; prefetch tiles 1,2 into two reg sets
  float4 a0x, a0y, a1x, a1y;
  if (wave < 4) {
    {
      int col = sc;
      const float* src = abase + (col >> 8) * 50176 + ((col >> 4) & 15) * 224;
      float4 p0 = *(const float4*)src;
      float4 p1 = *(const float4*)(src + 4);
      f16x8 hv; PACK8(hv, p0, p1);
      *(f16x8*)(As0 + adoff) = hv;
    }
    {
      int col = 32 + sc;
      const float* src = abase + (col >> 8) * 50176 + ((col >> 4) & 15) * 224;
      a0x = *(const float4*)src; a0y = *(const float4*)(src + 4);
    }
    {
      int col = 64 + sc;
      const float* src = abase + (col >> 8) * 50176 + ((col >> 4) & 15) * 224;
      a1x = *(const float4*)src; a1y = *(const float4*)(src + 4);
    }
  } else {
    gload16(gb0, Bs0 + lboff);
    gload16(gb0 + (size_t)16 * K, Bs0 + lboff + 16 * 32);
    gb0 += 32;
  }
  __syncthreads();

  f16* AsC = As0; f16* AsN = As1;
  f16* BsC = Bs0; f16* BsN = Bs1;

  for (int t = 0; t < NT; ++t) {
    if (wave < 4) {
      if (t + 1 < NT) {
        f16x8 hv;
        if ((t & 1) == 0) { PACK8(hv, a0x, a0y); }
        else              { PACK8(hv, a1x, a1y); }
        *(f16x8*)(AsN + adoff) = hv;
      }
      if (t + 3 < NT) {
        int col = (t + 3) * 32 + sc;
        const float* src = abase + (col >> 8) * 50176 + ((col >> 4) & 15) * 224;
        if ((t & 1) == 0) { a0x = *(const float4*)src; a0y = *(const float4*)(src + 4); }
        else              { a1x = *(const float4*)src; a1y = *(const float4*)(src + 4); }
      }
      // drain this wave's ds_write so AsN is visible after the barrier
      asm volatile("s_waitcnt lgkmcnt(0)" ::: "memory");
    } else {
      if (t + 1 < NT) {
        gload16(gb0, BsN + lboff);
        gload16(gb0 + (size_t)16 * K, BsN + lboff + 16 * 32);
        gb0 += 32;
        // allow the 2 just-issued (for buf t+1) to stay in flight; older done
        asm volatile("s_waitcnt vmcnt(2)" ::: "memory");
      } else {
        asm volatile("s_waitcnt vmcnt(0)" ::: "memory");
      }
    }
    __builtin_amdgcn_sched_barrier(0);
    __builtin_amdgcn_s_barrier();          // buf t fully staged for all waves
    __builtin_amdgcn_sched_barrier(0);

    f16x8 af = *(const f16x8*)&AsC[(rowgrp * 16 + fr) * 32 + swzR];
#pragma unroll
    for (int j = 0; j < 6; j++) {
      f16x8 bf = *(const f16x8*)&BsC[(colgrp * 96 + j * 16 + fr) * 32 + swzR];
      acc[j] = __builtin_amdgcn_mfma_f32_16x16x32_f16(af, bf, acc[j], 0, 0, 0);
    }
    // ensure this wave's ds_reads of buf t completed before signaling
    asm volatile("s_waitcnt lgkmcnt(0)" ::: "memory");
    __builtin_amdgcn_sched_barrier(0);
    __builtin_amdgcn_s_barrier();          // all waves done READING buf t
    __builtin_amdgcn_sched_barrier(0);
    f16* tA = AsC; AsC = AsN; AsN = tA;
    f16* tB = BsC; BsC = BsN; BsN = tB;
  }
  __syncthreads();   // full drain before LDS aliasing

  // ---- epilogue LDS (aliases staging storage) ----
  float* prm   = (float*)smem;              // 1152 f32
  float* psum  = (float*)(smem + 4608);     // 256 f32
  float* pqsum = (float*)(smem + 5632);     // 256 f32
  float* Rs2   = (float*)(smem + 6656);     // 2304 f32
  float* psc   = (float*)(smem + 15872);    // 1536 f32
  for (int i = tid; i < 1152; i += 1024)
    prm[i] = (i < 384) ? bias[i] : ((i < 768) ? g[i - 384] : bb[i - 768]);
  for (int i = tid; i < 2304; i += 1024) Rs2[i] = Rg[i];
  __syncthreads();

  float v[4][6];
#pragma unroll
  for (int rg = 0; rg < 4; rg++) {
    int lrow = rowgrp * 16 + fq * 4 + rg;
    int row = m0 + lrow;
    int bimg = row / 196;
    int pp = row - bimg * 196;
    const float* prow = posw + (size_t)(pp + 1) * EMB;
    float s = 0.f, sq = 0.f;
#pragma unroll
    for (int j = 0; j < 6; j++) {
      int col = colgrp * 96 + j * 16 + fr;
      float t = acc[j][rg] + prm[col] + prow[col];
      v[rg][j] = t;
      s += t; sq += t * t;
    }
#pragma unroll
    for (int off = 1; off < 16; off <<= 1) {
      s += __shfl_xor(s, off);
      sq += __shfl_xor(sq, off);
    }
    if (fr == 0) { psum[lrow * 4 + colgrp] = s; pqsum[lrow * 4 + colgrp] = sq; }
  }
  __syncthreads();

#pragma unroll
  for (int rg = 0; rg < 4; rg++) {
    int lrow = rowgrp * 16 + fq * 4 + rg;
    float S = psum[lrow * 4] + psum[lrow * 4 + 1] + psum[lrow * 4 + 2] + psum[lrow * 4 + 3];
    float SQ = pqsum[lrow * 4] + pqsum[lrow * 4 + 1] + pqsum[lrow * 4 + 2] + pqsum[lrow * 4 + 3];
    float m = S * (1.f / 384.f);
    float rs = rsqrtf(SQ * (1.f / 384.f) - m * m + 1e-5f);
    int row = m0 + lrow;
    int bimg = row / 196;
    int pp = row - bimg * 196;
    f16* orow = xh + ((size_t)bimg * NTOKC + pp + 1) * EMB;
#pragma unroll
    for (int j = 0; j < 6; j++) {
      int col = colgrp * 96 + j * 16 + fr;
      float y = (v[rg][j] - m) * rs * prm[384 + col] + prm[768 + col];
      v[rg][j] = y;
      orow[col] = (f16)y;
    }
  }

#pragma unroll
  for (int h = 0; h < 6; h++) {
    float rv[6];
#pragma unroll
    for (int j = 0; j < 6; j++)
      rv[j] = Rs2[h * 384 + colgrp * 96 + j * 16 + fr];
#pragma unroll
    for (int rg = 0; rg < 4; rg++) {
      float p = v[rg][0] * rv[0] + v[rg][1] * rv[1] + v[rg][2] * rv[2]
              + v[rg][3] * rv[3] + v[rg][4] * rv[4] + v[rg][5] * rv[5];
#pragma unroll
      for (int off = 1; off < 16; off <<= 1) p += __shfl_xor(p, off);
      if (fr == 0) psc[(rowgrp * 16 + fq * 4 + rg) * 24 + colgrp * 6 + h] = p;
    }
  }
  __syncthreads();
  if (tid < 384) {
    int lrow = tid / 6, h = tid - lrow * 6;
    float s = psc[lrow * 24 + h] + psc[lrow * 24 + 6 + h]
            + psc[lrow * 24 + 12 + h] + psc[lrow * 24 + 18 + h] + Cg[h];
    int row = m0 + lrow;
    int bimg = row / 196, pp = row - bimg * 196;
    Sg[((size_t)bimg * 6 + h) * 197 + pp + 1] = s;
  }
}

// ---------------- softmax (in-block) + u-GEMV -> U16 ---------------------------
// 512 thr: 8 token-slices of <=25 (halves the serial chain), 64 col-pairs.
__global__ __launch_bounds__(512) void u_gemv_k(
    const float* __restrict__ Sg, const f16* __restrict__ xh,
    f16* __restrict__ U16) {
  __shared__ float pf[6 * 208];        // 4992 B
  __shared__ float part[8][64][12];    // 24 KB
  const int cq = (int)blockIdx.x;
  const int b  = (int)blockIdx.y;
  const int tid = threadIdx.x;
  const int wave = tid >> 6, lane = tid & 63;

  if (wave < 6) {
    const float* sp = Sg + ((size_t)b * 6 + wave) * 197;
    float z[4], pk[4];
#pragma unroll
    for (int k = 0; k < 4; k++) {
      int t = lane + 64 * k;
      z[k] = (t < 197) ? sp[t] * 0.125f : -1e30f;
      pk[k] = 0.f;
    }
    float mx = fmaxf(fmaxf(z[0], z[1]), fmaxf(z[2], z[3]));
#pragma unroll
    for (int off = 32; off; off >>= 1) mx = fmaxf(mx, __shfl_xor(mx, off));
    float sum = 0.f;
#pragma unroll
    for (int k = 0; k < 4; k++) {
      int t = lane + 64 * k;
      if (t < 197) {
        pk[k] = __expf(z[k] - mx);
        sum += pk[k];
      }
    }
#pragma unroll
    for (int off = 32; off; off >>= 1) sum += __shfl_xor(sum, off);
    float si = 1.f / sum;
#pragma unroll
    for (int k = 0; k < 4; k++) {
      int t = lane + 64 * k;
      if (t < 208) pf[wave * 208 + t] = pk[k] * si;
    }
  }
  __syncthreads();

  const int cp = tid & 63;
  const int tq = tid >> 6;            // 0..7
  const int col0 = cq * 128 + cp * 2;
  const int t0 = 25 * tq;
  const int t1 = (t0 + 25 < 197) ? t0 + 25 : 197;
  float acc[12];
#pragma unroll
  for (int r = 0; r < 12; r++) acc[r] = 0.f;
  const f16* xp = xh + ((size_t)b * NTOKC + t0) * EMB + col0;
#pragma unroll 4
  for (int t = t0; t < t1; t++) {
    f16x2 xv = *(const f16x2*)xp;
    float x0 = (float)xv[0];
    float x1 = (float)xv[1];
    xp += EMB;
#pragma unroll
    for (int h = 0; h < 6; h++) {
      float p = pf[h * 208 + t];
      acc[h * 2]     += p * x0;
      acc[h * 2 + 1] += p * x1;
    }
  }
#pragma unroll
  for (int r = 0; r < 12; r++) part[tq][cp][r] = acc[r];
  __syncthreads();
  for (int idx = tid; idx < 768; idx += 512) {
    int cp2 = idx / 12, slot = idx - cp2 * 12;
    int h = slot >> 1, c01 = slot & 1;
    float u = 0.f;
#pragma unroll
    for (int q = 0; q < 8; q++) u += part[q][cp2][slot];
    U16[(size_t)b * 2304 + h * 384 + cq * 128 + cp2 * 2 + c01] = (f16)u;
  }
}

// ---------------- fused V+out projection: fpart[kc] = U16 @ F^T (split-K=6) -----
__global__ __launch_bounds__(256) void fproj_k(
    const f16* __restrict__ U16, const f16* __restrict__ F,
    float* __restrict__ fpart) {
  __shared__ f16 As[128 * 32];
  __shared__ f16 Bs[64 * 32];
  const int tid = threadIdx.x;
  const int lane = tid & 63;
  const int wave = tid >> 6;
  const int n0 = (int)blockIdx.x * 64;
  const int kc = (int)blockIdx.y;     // 0..5
  const int wm = (wave >> 1) * 64;
  const int wn = (wave & 1) * 32;
  const int fr = lane & 15;
  const int fq = lane >> 4;

  f32x4 acc[4][2];
#pragma unroll
  for (int i = 0; i < 4; i++)
#pragma unroll
    for (int j = 0; j < 2; j++) acc[i][j] = f32x4{0.f, 0.f, 0.f, 0.f};

  const int sr = lane >> 2;
  const int sc = (lane & 3) * 8;
  const f16* ag = U16 + (size_t)(wave * 32 + sr) * 2304 + kc * 384 + sc;
  const f16* bg = F + (size_t)(n0 + wave * 16 + sr) * 2304 + kc * 384 + sc;
  const size_t rstep = (size_t)16 * 2304;
  f16* la = As + wave * 32 * 32;
  f16* lb = Bs + wave * 16 * 32;

  for (int k0 = 0; k0 < 384; k0 += 32) {
    gload16(ag, la);  gload16(ag + rstep, la + 16 * 32);
    gload16(bg, lb);
    ag += 32; bg += 32;
    __syncthreads();
    f16x8 af[4], bf[2];
#pragma unroll
    for (int i = 0; i < 4; i++)
      af[i] = *(const f16x8*)&As[(wm + i * 16 + fr) * 32 + fq * 8];
#pragma unroll
    for (int j = 0; j < 2; j++)
      bf[j] = *(const f16x8*)&Bs[(wn + j * 16 + fr) * 32 + fq * 8];
#pragma unroll
    for (int i = 0; i < 4; i++)
#pragma unroll
      for (int j = 0; j < 2; j++)
        acc[i][j] = __builtin_amdgcn_mfma_f32_16x16x32_f16(af[i], bf[j], acc[i][j], 0, 0, 0);
    __syncthreads();
  }

#pragma unroll
  for (int i = 0; i < 4; i++)
#pragma unroll
    for (int j = 0; j < 2; j++)
#pragma unroll
      for (int rg = 0; rg < 4; rg++) {
        int gm = wm + i * 16 + fq * 4 + rg;
        int gn = n0 + wn + j * 16 + fr;
        fpart[((size_t)kc * 128 + gm) * EMB + gn] = acc[i][j][rg];
      }
}

// ---------------- combine fproj parts + bias2 + LN(ln1) + router top-2 ----------
__global__ __launch_bounds__(384) void ln_router_k(
    const float* __restrict__ fpart, const float* __restrict__ bias2,
    const float* __restrict__ g, const float* __restrict__ bb,
    const float* __restrict__ rw, const float* __restrict__ rb,
    f16* __restrict__ hcls16, float* __restrict__ maskw) {
  __shared__ float red[16];
  __shared__ float part[6][4];
  __shared__ float logits[4];
  int b = blockIdx.x, t = threadIdx.x;
  int lane = t & 63, wave = t >> 6;
  float v = bias2[t];
#pragma unroll
  for (int kc = 0; kc < 6; kc++)
    v += fpart[((size_t)kc * 128 + b) * EMB + t];
  float s = v, sq = v * v;
#pragma unroll
  for (int off = 32; off; off >>= 1) {
    s += __shfl_xor(s, off);
    sq += __shfl_xor(sq, off);
  }
  if (lane == 0) { red[wave] = s; red[8 + wave] = sq; }
  __syncthreads();
  float S = 0.f, SQ = 0.f;
#pragma unroll
  for (int i = 0; i < 6; i++) { S += red[i]; SQ += red[8 + i]; }
  float m = S * (1.f / 384.f);
  float rs = rsqrtf(SQ * (1.f / 384.f) - m * m + 1e-5f);
  float y = (v - m) * rs * g[t] + bb[t];
  hcls16[(size_t)b * EMB + t] = (f16)y;
  float p0 = y * rw[t];
  float p1 = y * rw[EMB + t];
  float p2 = y * rw[2 * EMB + t];
  float p3 = y * rw[3 * EMB + t];
#pragma unroll
  for (int off = 32; off; off >>= 1) {
    p0 += __shfl_xor(p0, off);
    p1 += __shfl_xor(p1, off);
    p2 += __shfl_xor(p2, off);
    p3 += __shfl_xor(p3, off);
  }
  if (lane == 0) { part[wave][0] = p0; part[wave][1] = p1; part[wave][2] = p2; part[wave][3] = p3; }
  __syncthreads();
  if (t < 4) {
    float a = rb[t];
#pragma unroll
    for (int i = 0; i < 6; i++) a += part[i][t];
    logits[t] = a;
  }
  __syncthreads();
  if (t == 0) {
    float l0 = logits[0], l1 = logits[1], l2 = logits[2], l3 = logits[3];
    int i1 = 0; float b1 = l0;
    if (l1 > b1) { b1 = l1; i1 = 1; }
    if (l2 > b1) { b1 = l2; i1 = 2; }
    if (l3 > b1) { b1 = l3; i1 = 3; }
    int i2 = -1; float b2 = 0.f;
    float lv[4] = {l0, l1, l2, l3};
#pragma unroll
    for (int i = 0; i < 4; i++) {
      if (i == i1) continue;
      if (i2 < 0 || lv[i] > b2) { i2 = i; b2 = lv[i]; }
    }
#pragma unroll
    for (int e = 0; e < 4; e++)
      maskw[(size_t)b * 4 + e] = (e == i1 || e == i2) ? 0.5f : 0.f;
  }
}

// ---------------- MoE GEMM1: hcls16[128x384] @ ew1t^T + GELU -> ehbuf f16 ---------
__global__ __launch_bounds__(256) void moe1_k(
    const f16* __restrict__ A, const f16* __restrict__ Bm,
    const float* __restrict__ bias, f16* __restrict__ outh) {
  __shared__ f16 As[128 * 32];
  __shared__ f16 Bs[64 * 32];
  const int K = EMB;
  const int tid = threadIdx.x;
  const int lane = tid & 63;
  const int wave = tid >> 6;
  const int e = (int)blockIdx.y;
  const int n0 = (int)blockIdx.x * 64;
  const int wm = (wave >> 1) * 64;
  const int wn = (wave & 1) * 32;
  const int fr = lane & 15;
  const int fq = lane >> 4;
  Bm += (size_t)e * HID * EMB;
  bias += (size_t)e * HID;

  f32x4 acc[4][2];
#pragma unroll
  for (int i = 0; i < 4; i++)
#pragma unroll
    for (int j = 0; j < 2; j++) acc[i][j] = f32x4{0.f, 0.f, 0.f, 0.f};

  const int sr = lane >> 2;
  const int sc = (lane & 3) * 8;
  const f16* ag = A + (size_t)(wave * 32 + sr) * K + sc;
  const f16* bg = Bm + (size_t)(n0 + wave * 16 + sr) * K + sc;
  const size_t rstep = (size_t)16 * K;
  f16* la = As + wave * 32 * 32;
  f16* lb = Bs + wave * 16 * 32;

  for (int k0 = 0; k0 < K; k0 += 32) {
    gload16(ag, la);  gload16(ag + rstep, la + 16 * 32);
    gload16(bg, lb);
    ag += 32; bg += 32;
    __syncthreads();
    f16x8 af[4], bf[2];
#pragma unroll
    for (int i = 0; i < 4; i++)
      af[i] = *(const f16x8*)&As[(wm + i * 16 + fr) * 32 + fq * 8];
#pragma unroll
    for (int j = 0; j < 2; j++)
      bf[j] = *(const f16x8*)&Bs[(wn + j * 16 + fr) * 32 + fq * 8];
#pragma unroll
    for (int i = 0; i < 4; i++)
#pragma unroll
      for (int j = 0; j < 2; j++)
        acc[i][j] = __builtin_amdgcn_mfma_f32_16x16x32_f16(af[i], bf[j], acc[i][j], 0, 0, 0);
    __syncthreads();
  }

#pragma unroll
  for (int i = 0; i < 4; i++)
#pragma unroll
    for (int j = 0; j < 2; j++)
#pragma unroll
      for (int rg = 0; rg < 4; rg++) {
        int gm = wm + i * 16 + fq * 4 + rg;
        int gn = n0 + wn + j * 16 + fr;
        float v = acc[i][j][rg] + bias[gn];
        float gl = 0.5f * v * (1.0f + erff(v * 0.70710678118654752f));
        outh[(size_t)e * 128 * HID + (size_t)gm * HID + gn] = (f16)gl;
      }
}

// ---------------- MoE GEMM2 split-K ----------------
__global__ __launch_bounds__(256) void moe2_k(
    const f16* __restrict__ EH, const f16* __restrict__ W2,
    float* __restrict__ part) {
  __shared__ f16 As[128 * 32];
  __shared__ f16 Bs[64 * 32];
  const int tid = threadIdx.x;
  const int lane = tid & 63;
  const int wave = tid >> 6;
  const int n0 = (int)blockIdx.x * 64;
  const int e = (int)blockIdx.y;
  const int kc = (int)blockIdx.z;
  const int wm = (wave >> 1) * 64;
  const int wn = (wave & 1) * 32;
  const int fr = lane & 15;
  const int fq = lane >> 4;
  const f16* A = EH + (size_t)e * 128 * HID + kc * 384;
  const f16* B = W2 + (size_t)e * EMB * HID + kc * 384;

  f32x4 acc[4][2];
#pragma unroll
  for (int i = 0; i < 4; i++)
#pragma unroll
    for (int j = 0; j < 2; j++) acc[i][j] = f32x4{0.f, 0.f, 0.f, 0.f};

  const int sr = lane >> 2;
  const int sc = (lane & 3) * 8;
  const f16* ag = A + (size_t)(wave * 32 + sr) * HID + sc;
  const f16* bg = B + (size_t)(n0 + wave * 16 + sr) * HID + sc;
  const size_t rstep = (size_t)16 * HID;
  f16* la = As + wave * 32 * 32;
  f16* lb = Bs + wave * 16 * 32;

  for (int k0 = 0; k0 < 384; k0 += 32) {
    gload16(ag, la);  gload16(ag + rstep, la + 16 * 32);
    gload16(bg, lb);
    ag += 32; bg += 32;
    __syncthreads();
    f16x8 af[4], bf[2];
#pragma unroll
    for (int i = 0; i < 4; i++)
      af[i] = *(const f16x8*)&As[(wm + i * 16 + fr) * 32 + fq * 8];
#pragma unroll
    for (int j = 0; j < 2; j++)
      bf[j] = *(const f16x8*)&Bs[(wn + j * 16 + fr) * 32 + fq * 8];
#pragma unroll
    for (int i = 0; i < 4; i++)
#pragma unroll
      for (int j = 0; j < 2; j++)
        acc[i][j] = __builtin_amdgcn_mfma_f32_16x16x32_f16(af[i], bf[j], acc[i][j], 0, 0, 0);
    __syncthreads();
  }

#pragma unroll
  for (int i = 0; i < 4; i++)
#pragma unroll
    for (int j = 0; j < 2; j++)
#pragma unroll
      for (int rg = 0; rg < 4; rg++) {
        int gm = wm + i * 16 + fq * 4 + rg;
        int gn = n0 + wn + j * 16 + fr;
        part[(((size_t)kc * 4 + e) * 128 + gm) * EMB + gn] = acc[i][j][rg];
      }
}

// ---------------- combine split-K + experts + LN2 -> f16 ----------------
__global__ __launch_bounds__(384) void combine_ln2_k(
    const float* __restrict__ part, const float* __restrict__ eb2,
    const float* __restrict__ maskw,
    const float* __restrict__ g, const float* __restrict__ bb,
    f16* __restrict__ hfin) {
  __shared__ float red[16];
  int b = blockIdx.x, t = threadIdx.x;
  int lane = t & 63, wave = t >> 6;
  float v = 0.f;
#pragma unroll
  for (int e = 0; e < 4; e++) {
    float s = eb2[e * EMB + t];
#pragma unroll
    for (int kc = 0; kc < 4; kc++)
      s += part[(((size_t)kc * 4 + e) * 128 + b) * EMB + t];
    v += maskw[b * 4 + e] * s;
  }
  float s = v, sq = v * v;
#pragma unroll
  for (int off = 32; off; off >>= 1) {
    s += __shfl_xor(s, off);
    sq += __shfl_xor(sq, off);
  }
  if (lane == 0) { red[wave] = s; red[8 + wave] = sq; }
  __syncthreads();
  float S = 0.f, SQ = 0.f;
#pragma unroll
  for (int i = 0; i < 6; i++) { S += red[i]; SQ += red[8 + i]; }
  float m = S * (1.f / 384.f);
  float rs = rsqrtf(SQ * (1.f / 384.f) - m * m + 1e-5f);
  hfin[(size_t)b * EMB + t] = (f16)((v - m) * rs * g[t] + bb[t]);
}

// ---------------- head GEMM ----------------
__global__ __launch_bounds__(256) void head_gemm_k(
    const f16* __restrict__ A, const f16* __restrict__ B,
    const float* __restrict__ hb, float* __restrict__ outp) {
  __shared__ f16 As[128 * 32];
  __shared__ f16 Bs[128 * 32];
  const int K = 384;
  const int tid = threadIdx.x;
  const int lane = tid & 63;
  const int wave = tid >> 6;
  const int n0 = (int)blockIdx.x * 128;
  const int wm = (wave >> 1) * 64;
  const int wn = (wave & 1) * 64;
  const int fr = lane & 15;
  const int fq = lane >> 4;

  f32x4 acc[4][4];
#pragma unroll
  for (int i = 0; i < 4; i++)
#pragma unroll
    for (int j = 0; j < 4; j++) acc[i][j] = f32x4{0.f, 0.f, 0.f, 0.f};

  const int srow = wave * 32 + (lane >> 2);
  const int scol = (lane & 3) * 8;
  const f16* ag = A + (size_t)srow * K + scol;
  const f16* bg = B + (size_t)(n0 + srow) * K + scol;
  const size_t rstep = (size_t)16 * K;
  f16* la = As + wave * 32 * 32;
  f16* lb = Bs + wave * 32 * 32;

  for (int k0 = 0; k0 < K; k0 += 32) {
    gload16(ag, la);          gload16(ag + rstep, la + 16 * 32);
    gload16(bg, lb);          gload16(bg + rstep, lb + 16 * 32);
    ag += 32; bg += 32;
    __syncthreads();
    f16x8 af[4], bf[4];
#pragma unroll
    for (int i = 0; i < 4; i++) {
      af[i] = *(const f16x8*)&As[(wm + i * 16 + fr) * 32 + fq * 8];
      bf[i] = *(const f16x8*)&Bs[(wn + i * 16 + fr) * 32 + fq * 8];
    }
#pragma unroll
    for (int i = 0; i < 4; i++)
#pragma unroll
      for (int j = 0; j < 4; j++)
        acc[i][j] = __builtin_amdgcn_mfma_f32_16x16x32_f16(af[i], bf[j], acc[i][j], 0, 0, 0);
    __syncthreads();
  }

#pragma unroll
  for (int i = 0; i < 4; i++)
#pragma unroll
    for (int j = 0; j < 4; j++)
#pragma unroll
      for (int rg = 0; rg < 4; rg++) {
        int gm = wm + i * 16 + fq * 4 + rg;
        int gn = n0 + wn + j * 16 + fr;
        if (gn < 1000)
          outp[(size_t)gm * 1000 + gn] = acc[i][j][rg] + hb[gn];
      }
}

// ---------------- host ----------------
extern "C" void kernel_launch(void* const* d_in, const int* in_sizes, int n_in,
                              void* d_out, int out_size, void* d_ws, size_t ws_size,
                              hipStream_t stream) {
  const float* x      = (const float*)d_in[0];
  const float* conv_w = (const float*)d_in[1];
  const float* conv_b = (const float*)d_in[2];
  const float* cls_t  = (const float*)d_in[3];
  const float* pos    = (const float*)d_in[4];
  const float* ln1_g  = (const float*)d_in[5];
  const float* ln1_b  = (const float*)d_in[6];
  const float* inp_w  = (const float*)d_in[7];
  const float* inp_b  = (const float*)d_in[8];
  const float* outp_w = (const float*)d_in[9];
  const float* outp_b = (const float*)d_in[10];
  const float* rt_w   = (const float*)d_in[11];
  const float* rt_b   = (const float*)d_in[12];
  const float* ew1    = (const float*)d_in[13];
  const float* eb1    = (const float*)d_in[14];
  const float* ew2    = (const float*)d_in[15];
  const float* eb2    = (const float*)d_in[16];
  const float* ln2_g  = (const float*)d_in[17];
  const float* ln2_b  = (const float*)d_in[18];
  const float* head_w = (const float*)d_in[19];
  const float* head_b = (const float*)d_in[20];
  float* out = (float*)d_out;
  char* w = (char*)d_ws;
  if (ws_size < WS_NEEDED) return;

  f16* convw    = (f16*)(w + OFF_CONVW);
  f16* ew1t     = (f16*)(w + OFF_EW1T);
  f16* ew2t     = (f16*)(w + OFF_EW2T);
  f16* headw16  = (f16*)(w + OFF_HEADW16);
  f16* xcls16   = (f16*)(w + OFF_XCLS16);
  f16* hcls16   = (f16*)(w + OFF_HCLS16);
  float* maskw  = (float*)(w + OFF_MASKW);
  f16* ehbuf    = (f16*)(w + OFF_EH);
  float* epart  = (float*)(w + OFF_EPART);
  f16* hfin     = (f16*)(w + OFF_HFIN);
  f16* xh       = (f16*)(w + OFF_XH);
  float* Rg     = (float*)(w + OFF_R);
  float* Cg     = (float*)(w + OFF_CVEC);
  f16* u16      = (f16*)(w + OFF_U16);
  float* sg     = (float*)(w + OFF_SG);
  float* scls   = (float*)(w + OFF_SCLS);
  f16* Fw       = (f16*)(w + OFF_F);
  float* bias2  = (float*)(w + OFF_B2);
  float* fpart  = (float*)(w + OFF_FPART);

  // ---- all weight prep (casts + transposes + Wfused + bias2) in one launch ----
  prep_all_k<<<dim3(7464), 256, 0, stream>>>(
      conv_w, head_w, ew1, ew2, inp_w, inp_b, outp_w, outp_b,
      convw, headw16, ew1t, ew2t, Fw, bias2);

  // ---- cls LN + q/r/c/Scls precompute (one launch) ----
  clsrprep_k<<<dim3(6), 384, 0, stream>>>(
      cls_t, pos, ln1_g, ln1_b, inp_w, inp_b, xcls16, Rg, Cg, scls);

  // ---- fused implicit-im2col embed GEMM + LN1 + score epilogue + cls bcast ----
  embed_ln_k<<<dim3(392), 1024, 0, stream>>>(
      x, convw, conv_b, pos, ln1_g, ln1_b, Rg, Cg, xcls16, scls, xh, sg);

  // ---- softmax + u-GEMV -> U16 (512 thr, 8 token-slices) ----
  u_gemv_k<<<dim3(3, 128), 512, 0, stream>>>(sg, xh, u16);

  // ---- fused V+out projection (split-K=6) + combine/LN/router ----
  fproj_k<<<dim3(6, 6), 256, 0, stream>>>(u16, Fw, fpart);
  ln_router_k<<<dim3(128), 384, 0, stream>>>(
      fpart, bias2, ln1_g, ln1_b, rt_w, rt_b, hcls16, maskw);

  // ---- MoE ----
  moe1_k<<<dim3(24, 4), 256, 0, stream>>>(hcls16, ew1t, eb1, ehbuf);
  moe2_k<<<dim3(6, 4, 4), 256, 0, stream>>>(ehbuf, ew2t, epart);
  combine_ln2_k<<<dim3(128), 384, 0, stream>>>(epart, eb2, maskw, ln2_g, ln2_b, hfin);

  // ---- head ----
  head_gemm_k<<<dim3(8), 256, 0, stream>>>(hfin, headw16, head_b, out);
  (void)in_sizes; (void)n_in; (void)out_size;
}

// Round 13
// 338.851 us; speedup vs baseline: 1.0479x; 1.0479x over previous
//
#include <hip/hip_runtime.h>
#include <cstdint>
#include <cstddef>

typedef _Float16 f16;
typedef _Float16 f16x2 __attribute__((ext_vector_type(2)));
typedef _Float16 f16x8 __attribute__((ext_vector_type(8)));
typedef float    f32x4 __attribute__((ext_vector_type(4)));

// ---------------- problem constants ----------------
constexpr int NTOKC  = 197;
constexpr int TTOK   = 128 * 197;         // 25216
constexpr int EMB    = 384;
constexpr int HID    = 1536;

// ---------------- workspace layout (bytes) ----------------
constexpr size_t OFF_CONVW   = 0;                        // 384*768 f16
constexpr size_t OFF_EW1T    = 1179648;                  // 4*1536*384 f16
constexpr size_t OFF_EW2T    = 5898240;                  // 4*384*1536 f16
constexpr size_t OFF_HEADW16 = 10616832;                 // 1024*384 f16
constexpr size_t OFF_XCLS16  = 11403264;                 // 384 f16
constexpr size_t OFF_HCLS16  = 11799552;                 // 128*384 f16
constexpr size_t OFF_MASKW   = 11897856;                 // 128*4 f32
constexpr size_t OFF_EH      = 11899904;                 // 4*128*1536 f16
constexpr size_t OFF_EPART   = 13472768;                 // 4kc*4e*128*384 f32
constexpr size_t OFF_HFIN    = 16618496;                 // 128*384 f16
constexpr size_t OFF_XH      = 16716800;                 // TTOK*384 f16
constexpr size_t OFF_R       = 36082688;                 // 6*384 f32
constexpr size_t OFF_CVEC    = 36094976;                 // 6 f32
constexpr size_t OFF_U16     = 36099072;                 // 128*2304 f16
constexpr size_t OFF_SG      = 38212608;                 // 128*6*197 f32
constexpr size_t OFF_SCLS    = 38817792;                 // 6 f32
constexpr size_t OFF_F       = 38818816;                 // 384*2304 f16
constexpr size_t OFF_B2      = 40588288;                 // 384 f32
constexpr size_t OFF_FPART   = 40589824;                 // 6kc*128*384 f32
constexpr size_t WS_NEEDED   = 41769472;                 // ~41.8 MB

// ---------------- global_load_lds helper ----------------
__device__ __forceinline__ void gload16(const void* g, void* l) {
  __builtin_amdgcn_global_load_lds(
      (__attribute__((address_space(1))) void*)(void*)g,
      (__attribute__((address_space(3))) void*)l, 16, 0, 0);
}

#define PACK8(hv, p0, p1) { hv[0]=(f16)p0.x; hv[1]=(f16)p0.y; hv[2]=(f16)p0.z; hv[3]=(f16)p0.w; \
                            hv[4]=(f16)p1.x; hv[5]=(f16)p1.y; hv[6]=(f16)p1.z; hv[7]=(f16)p1.w; }

// ---------------- ALL weight prep in ONE launch --------------------------------
// bx ranges: [0,2688) casts | [2688,4992) ew1 transpose | [4992,7296) ew2 transpose
//            [7296,7440) Wfused | [7440,7464) bias2
__global__ __launch_bounds__(256) void prep_all_k(
    const float* __restrict__ conv_w, const float* __restrict__ head_w,
    const float* __restrict__ ew1, const float* __restrict__ ew2,
    const float* __restrict__ inp_w, const float* __restrict__ inp_b,
    const float* __restrict__ outp_w, const float* __restrict__ outp_b,
    f16* __restrict__ convw, f16* __restrict__ headw16,
    f16* __restrict__ ew1t, f16* __restrict__ ew2t,
    f16* __restrict__ F, float* __restrict__ bias2) {
  __shared__ __attribute__((aligned(16))) char sbuf[4352];
  const int bx = (int)blockIdx.x, tid = threadIdx.x;
  if (bx < 2688) {
    int i = bx * 256 + tid;
    if (i < 294912) convw[i] = (f16)conv_w[i];
    int j = i - 294912;
    if (j >= 0 && j < 393216) {
      int row = j / 384;
      headw16[j] = (row < 1000) ? (f16)head_w[j] : (f16)0.f;
    }
  } else if (bx < 4992) {
    float (*tile)[33] = (float(*)[33])sbuf;
    int local = bx - 2688;
    int e = local / 576, r2 = local - e * 576;
    int byy = r2 / 48, bxx = r2 - byy * 48;
    const float* pin = ew1 + (size_t)e * 384 * 1536;
    f16* pout = ew1t + (size_t)e * 384 * 1536;
    int c0 = bxx * 32, r0 = byy * 32;
    int tx = tid & 31, ty = tid >> 5;
#pragma unroll
    for (int i = 0; i < 4; i++)
      tile[ty + 8 * i][tx] = pin[(size_t)(r0 + ty + 8 * i) * 1536 + c0 + tx];
    __syncthreads();
#pragma unroll
    for (int i = 0; i < 4; i++)
      pout[(size_t)(c0 + ty + 8 * i) * 384 + r0 + tx] = (f16)tile[tx][ty + 8 * i];
  } else if (bx < 7296) {
    float (*tile)[33] = (float(*)[33])sbuf;
    int local = bx - 4992;
    int e = local / 576, r2 = local - e * 576;
    int byy = r2 / 12, bxx = r2 - byy * 12;
    const float* pin = ew2 + (size_t)e * 1536 * 384;
    f16* pout = ew2t + (size_t)e * 1536 * 384;
    int c0 = bxx * 32, r0 = byy * 32;
    int tx = tid & 31, ty = tid >> 5;
#pragma unroll
    for (int i = 0; i < 4; i++)
      tile[ty + 8 * i][tx] = pin[(size_t)(r0 + ty + 8 * i) * 384 + c0 + tx];
    __syncthreads();
#pragma unroll
    for (int i = 0; i < 4; i++)
      pout[(size_t)(c0 + ty + 8 * i) * 1536 + r0 + tx] = (f16)tile[tx][ty + 8 * i];
  } else if (bx < 7440) {
    // F[n][h*384+k] = sum_d Wout[n][h*64+d] * Wv[h*64+d][k]
    float (*wo)[64] = (float(*)[64])sbuf;   // [16][64]
    int local = bx - 7296;
    int h = local / 24, nt = local - h * 24;
    int n0 = nt * 16;
    for (int i = tid; i < 1024; i += 256) {
      int ni = i >> 6, d = i & 63;
      wo[ni][d] = outp_w[(size_t)(n0 + ni) * 384 + h * 64 + d];
    }
    __syncthreads();
    for (int e = tid; e < 6144; e += 256) {
      int ni = e / 384, k2 = e - ni * 384;
      const float* wv = inp_w + (size_t)(768 + h * 64) * 384 + k2;
      float a = 0.f;
#pragma unroll 8
      for (int d = 0; d < 64; d++) a += wo[ni][d] * wv[(size_t)d * 384];
      F[(size_t)(n0 + ni) * 2304 + h * 384 + k2] = (f16)a;
    }
  } else {
    // bias2[n] = bout[n] + sum_c Wout[n][c]*bv[c]
    int nt = bx - 7440;
    if (tid < 16) {
      int n = nt * 16 + tid;
      const float* wrow = outp_w + (size_t)n * 384;
      float a = outp_b[n];
      for (int c = 0; c < 384; c++) a += wrow[c] * inp_b[768 + c];
      bias2[n] = a;
    }
  }
}

// ---------------- cls LN + q_h + r_h + c_h + Scls_h (one launch, 6 blocks) -----
__global__ __launch_bounds__(384) void clsrprep_k(
    const float* __restrict__ cls, const float* __restrict__ posw,
    const float* __restrict__ g, const float* __restrict__ bb,
    const float* __restrict__ inp_w, const float* __restrict__ inp_b,
    f16* __restrict__ xcls16, float* __restrict__ Rg,
    float* __restrict__ Cg, float* __restrict__ Scls) {
  __shared__ float xs[EMB];
  __shared__ float red[16];
  __shared__ float qh[64];
  __shared__ float sred[6];
  const int h = (int)blockIdx.x, t = threadIdx.x;
  const int lane = t & 63, wave = t >> 6;
  float v = cls[t] + posw[t];
  float s = v, sq = v * v;
#pragma unroll
  for (int off = 32; off; off >>= 1) {
    s += __shfl_xor(s, off);
    sq += __shfl_xor(sq, off);
  }
  if (lane == 0) { red[wave] = s; red[8 + wave] = sq; }
  __syncthreads();
  float S = 0.f, SQ = 0.f;
#pragma unroll
  for (int i = 0; i < 6; i++) { S += red[i]; SQ += red[8 + i]; }
  float m = S * (1.f / 384.f);
  float rs = rsqrtf(SQ * (1.f / 384.f) - m * m + 1e-5f);
  float y = (v - m) * rs * g[t] + bb[t];
  xs[t] = y;
  xcls16[t] = (f16)y;      // redundant identical writes across blocks: benign
  __syncthreads();
  if (t < 64) {
    const float* wq = inp_w + (size_t)(h * 64 + t) * 384;
    float a = inp_b[h * 64 + t];
#pragma unroll 8
    for (int c = 0; c < 384; c++) a += wq[c] * xs[c];
    qh[t] = a;
  }
  __syncthreads();
  const float* wp = inp_w + (size_t)(384 + h * 64) * 384 + t;
  float a = 0.f;
#pragma unroll 8
  for (int d = 0; d < 64; d++) a += wp[(size_t)d * 384] * qh[d];
  Rg[h * 384 + t] = a;
  float part = a * xs[t];
#pragma unroll
  for (int off = 32; off; off >>= 1) part += __shfl_xor(part, off);
  if (lane == 0) sred[wave] = part;
  __syncthreads();
  if (t == 0) {
    float c = 0.f;
    for (int d = 0; d < 64; d++) c += qh[d] * inp_b[384 + h * 64 + d];
    Cg[h] = c;
    float st = c;
#pragma unroll
    for (int i = 0; i < 6; i++) st += sred[i];
    Scls[h] = st;
  }
}

// ---------------- fused implicit-im2col embed GEMM + LN1 + score epilogue ------
// dbuf single-barrier K-loop; chunk-XOR LDS swizzle (both-sides); A-prefetch d=2;
// blocks 0..127 also broadcast the cls row + cls score.  [round-11 verified]
__global__ __launch_bounds__(1024) void embed_ln_k(
    const float* __restrict__ img, const f16* __restrict__ B,
    const float* __restrict__ bias, const float* __restrict__ posw,
    const float* __restrict__ g, const float* __restrict__ bb,
    const float* __restrict__ Rg, const float* __restrict__ Cg,
    const f16* __restrict__ xcls16, const float* __restrict__ Scls,
    f16* __restrict__ xh, float* __restrict__ Sg) {
  __shared__ __attribute__((aligned(16))) char smem[57344];
  f16* As0 = (f16*)smem;
  f16* As1 = (f16*)(smem + 4096);
  f16* Bs0 = (f16*)(smem + 8192);
  f16* Bs1 = (f16*)(smem + 32768);
  const int K = 768;
  const int NT = 24;
  const int tid = threadIdx.x;
  const int lane = tid & 63;
  const int wave = tid >> 6;
  const int rowgrp = wave & 3;
  const int colgrp = wave >> 2;
  const int m0 = (int)blockIdx.x * 64;
  const int fr = lane & 15;
  const int fq = lane >> 4;

  // folded cls broadcast
  if (blockIdx.x < 128) {
    if (tid < 384) xh[(size_t)blockIdx.x * NTOKC * EMB + tid] = xcls16[tid];
    if (tid < 6) Sg[((size_t)blockIdx.x * 6 + tid) * 197] = Scls[tid];
  }

  f32x4 acc[6];
#pragma unroll
  for (int j = 0; j < 6; j++) acc[j] = f32x4{0.f, 0.f, 0.f, 0.f};

  const int sr = lane >> 2, sc = (lane & 3) * 8;
  const int swzS = (((lane & 3) ^ (sr & 3)) * 8);   // staging swizzled chunk (halfwords)
  const int swzR = ((fq ^ (fr & 3)) * 8);           // read swizzled chunk

  const float* abase = nullptr;
  int adoff = 0;
  if (wave < 4) {
    int row = m0 + wave * 16 + sr;
    int bimg = row / 196;
    int pp = row - bimg * 196;
    int py = pp / 14, px = pp - py * 14;
    int kx0 = sc & 15;
    abase = img + ((size_t)(bimg * 3) * 224 + py * 16) * 224 + px * 16 + kx0;
    adoff = (wave * 16 + sr) * 32 + swzS;           // swizzled LDS dest
  }
  const f16* gb0 = nullptr;
  int lboff = 0;
  if (wave >= 4) {
    int brow = (wave - 4) * 32;
    gb0 = B + (size_t)(brow + sr) * K + swzS;       // pre-swizzled GLOBAL source
    lboff = brow * 32;                              // linear LDS dest
  }

  // prologue: stage tile0; prefetch tiles 1,2 into two reg sets
  float4 a0x, a0y, a1x, a1y;
  if (wave < 4) {
    {
      int col = sc;
      const float* src = abase + (col >> 8) * 50176 + ((col >> 4) & 15) * 224;
      float4 p0 = *(const float4*)src;
      float4 p1 = *(const float4*)(src + 4);
      f16x8 hv; PACK8(hv, p0, p1);
      *(f16x8*)(As0 + adoff) = hv;
    }
    {
      int col = 32 + sc;
      const float* src = abase + (col >> 8) * 50176 + ((col >> 4) & 15) * 224;
      a0x = *(const float4*)src; a0y = *(const float4*)(src + 4);
    }
    {
      int col = 64 + sc;
      const float* src = abase + (col >> 8) * 50176 + ((col >> 4) & 15) * 224;
      a1x = *(const float4*)src; a1y = *(const float4*)(src + 4);
    }
  } else {
    gload16(gb0, Bs0 + lboff);
    gload16(gb0 + (size_t)16 * K, Bs0 + lboff + 16 * 32);
    gb0 += 32;
  }
  __syncthreads();

  f16* AsC = As0; f16* AsN = As1;
  f16* BsC = Bs0; f16* BsN = Bs1;

  for (int t = 0; t < NT; ++t) {
    if (wave < 4) {
      if (t + 1 < NT) {
        f16x8 hv;
        if ((t & 1) == 0) { PACK8(hv, a0x, a0y); }
        else              { PACK8(hv, a1x, a1y); }
        *(f16x8*)(AsN + adoff) = hv;
      }
      if (t + 3 < NT) {
        int col = (t + 3) * 32 + sc;
        const float* src = abase + (col >> 8) * 50176 + ((col >> 4) & 15) * 224;
        if ((t & 1) == 0) { a0x = *(const float4*)src; a0y = *(const float4*)(src + 4); }
        else              { a1x = *(const float4*)src; a1y = *(const float4*)(src + 4); }
      }
    } else {
      if (t + 1 < NT) {
        gload16(gb0, BsN + lboff);
        gload16(gb0 + (size_t)16 * K, BsN + lboff + 16 * 32);
        gb0 += 32;
      }
    }
    f16x8 af = *(const f16x8*)&AsC[(rowgrp * 16 + fr) * 32 + swzR];
#pragma unroll
    for (int j = 0; j < 6; j++) {
      f16x8 bf = *(const f16x8*)&BsC[(colgrp * 96 + j * 16 + fr) * 32 + swzR];
      acc[j] = __builtin_amdgcn_mfma_f32_16x16x32_f16(af, bf, acc[j], 0, 0, 0);
    }
    __syncthreads();
    f16* tA = AsC; AsC = AsN; AsN = tA;
    f16* tB = BsC; BsC = BsN; BsN = tB;
  }

  // ---- epilogue LDS (aliases staging storage) ----
  float* prm   = (float*)smem;              // 1152 f32
  float* psum  = (float*)(smem + 4608);     // 256 f32
  float* pqsum = (float*)(smem + 5632);     // 256 f32
  float* Rs2   = (float*)(smem + 6656);     // 2304 f32
  float* psc   = (float*)(smem + 15872);    // 1536 f32
  for (int i = tid; i < 1152; i += 1024)
    prm[i] = (i < 384) ? bias[i] : ((i < 768) ? g[i - 384] : bb[i - 768]);
  for (int i = tid; i < 2304; i += 1024) Rs2[i] = Rg[i];
  __syncthreads();

  float v[4][6];
#pragma unroll
  for (int rg = 0; rg < 4; rg++) {
    int lrow = rowgrp * 16 + fq * 4 + rg;
    int row = m0 + lrow;
    int bimg = row / 196;
    int pp = row - bimg * 196;
    const float* prow = posw + (size_t)(pp + 1) * EMB;
    float s = 0.f, sq = 0.f;
#pragma unroll
    for (int j = 0; j < 6; j++) {
      int col = colgrp * 96 + j * 16 + fr;
      float t = acc[j][rg] + prm[col] + prow[col];
      v[rg][j] = t;
      s += t; sq += t * t;
    }
#pragma unroll
    for (int off = 1; off < 16; off <<= 1) {
      s += __shfl_xor(s, off);
      sq += __shfl_xor(sq, off);
    }
    if (fr == 0) { psum[lrow * 4 + colgrp] = s; pqsum[lrow * 4 + colgrp] = sq; }
  }
  __syncthreads();

#pragma unroll
  for (int rg = 0; rg < 4; rg++) {
    int lrow = rowgrp * 16 + fq * 4 + rg;
    float S = psum[lrow * 4] + psum[lrow * 4 + 1] + psum[lrow * 4 + 2] + psum[lrow * 4 + 3];
    float SQ = pqsum[lrow * 4] + pqsum[lrow * 4 + 1] + pqsum[lrow * 4 + 2] + pqsum[lrow * 4 + 3];
    float m = S * (1.f / 384.f);
    float rs = rsqrtf(SQ * (1.f / 384.f) - m * m + 1e-5f);
    int row = m0 + lrow;
    int bimg = row / 196;
    int pp = row - bimg * 196;
    f16* orow = xh + ((size_t)bimg * NTOKC + pp + 1) * EMB;
#pragma unroll
    for (int j = 0; j < 6; j++) {
      int col = colgrp * 96 + j * 16 + fr;
      float y = (v[rg][j] - m) * rs * prm[384 + col] + prm[768 + col];
      v[rg][j] = y;
      orow[col] = (f16)y;
    }
  }

#pragma unroll
  for (int h = 0; h < 6; h++) {
    float rv[6];
#pragma unroll
    for (int j = 0; j < 6; j++)
      rv[j] = Rs2[h * 384 + colgrp * 96 + j * 16 + fr];
#pragma unroll
    for (int rg = 0; rg < 4; rg++) {
      float p = v[rg][0] * rv[0] + v[rg][1] * rv[1] + v[rg][2] * rv[2]
              + v[rg][3] * rv[3] + v[rg][4] * rv[4] + v[rg][5] * rv[5];
#pragma unroll
      for (int off = 1; off < 16; off <<= 1) p += __shfl_xor(p, off);
      if (fr == 0) psc[(rowgrp * 16 + fq * 4 + rg) * 24 + colgrp * 6 + h] = p;
    }
  }
  __syncthreads();
  if (tid < 384) {
    int lrow = tid / 6, h = tid - lrow * 6;
    float s = psc[lrow * 24 + h] + psc[lrow * 24 + 6 + h]
            + psc[lrow * 24 + 12 + h] + psc[lrow * 24 + 18 + h] + Cg[h];
    int row = m0 + lrow;
    int bimg = row / 196, pp = row - bimg * 196;
    Sg[((size_t)bimg * 6 + h) * 197 + pp + 1] = s;
  }
}

// ---------------- softmax (in-block) + u-GEMV -> U16 ---------------------------
// 512 thr: 8 token-slices of <=25 (halves the serial chain), 64 col-pairs.
__global__ __launch_bounds__(512) void u_gemv_k(
    const float* __restrict__ Sg, const f16* __restrict__ xh,
    f16* __restrict__ U16) {
  __shared__ float pf[6 * 208];        // 4992 B
  __shared__ float part[8][64][12];    // 24 KB
  const int cq = (int)blockIdx.x;
  const int b  = (int)blockIdx.y;
  const int tid = threadIdx.x;
  const int wave = tid >> 6, lane = tid & 63;

  if (wave < 6) {
    const float* sp = Sg + ((size_t)b * 6 + wave) * 197;
    float z[4], pk[4];
#pragma unroll
    for (int k = 0; k < 4; k++) {
      int t = lane + 64 * k;
      z[k] = (t < 197) ? sp[t] * 0.125f : -1e30f;
      pk[k] = 0.f;
    }
    float mx = fmaxf(fmaxf(z[0], z[1]), fmaxf(z[2], z[3]));
#pragma unroll
    for (int off = 32; off; off >>= 1) mx = fmaxf(mx, __shfl_xor(mx, off));
    float sum = 0.f;
#pragma unroll
    for (int k = 0; k < 4; k++) {
      int t = lane + 64 * k;
      if (t < 197) {
        pk[k] = __expf(z[k] - mx);
        sum += pk[k];
      }
    }
#pragma unroll
    for (int off = 32; off; off >>= 1) sum += __shfl_xor(sum, off);
    float si = 1.f / sum;
#pragma unroll
    for (int k = 0; k < 4; k++) {
      int t = lane + 64 * k;
      if (t < 208) pf[wave * 208 + t] = pk[k] * si;
    }
  }
  __syncthreads();

  const int cp = tid & 63;
  const int tq = tid >> 6;            // 0..7
  const int col0 = cq * 128 + cp * 2;
  const int t0 = 25 * tq;
  const int t1 = (t0 + 25 < 197) ? t0 + 25 : 197;
  float acc[12];
#pragma unroll
  for (int r = 0; r < 12; r++) acc[r] = 0.f;
  const f16* xp = xh + ((size_t)b * NTOKC + t0) * EMB + col0;
#pragma unroll 4
  for (int t = t0; t < t1; t++) {
    f16x2 xv = *(const f16x2*)xp;
    float x0 = (float)xv[0];
    float x1 = (float)xv[1];
    xp += EMB;
#pragma unroll
    for (int h = 0; h < 6; h++) {
      float p = pf[h * 208 + t];
      acc[h * 2]     += p * x0;
      acc[h * 2 + 1] += p * x1;
    }
  }
#pragma unroll
  for (int r = 0; r < 12; r++) part[tq][cp][r] = acc[r];
  __syncthreads();
  for (int idx = tid; idx < 768; idx += 512) {
    int cp2 = idx / 12, slot = idx - cp2 * 12;
    int h = slot >> 1, c01 = slot & 1;
    float u = 0.f;
#pragma unroll
    for (int q = 0; q < 8; q++) u += part[q][cp2][slot];
    U16[(size_t)b * 2304 + h * 384 + cq * 128 + cp2 * 2 + c01] = (f16)u;
  }
}

// ---------------- fused V+out projection: fpart[kc] = U16 @ F^T (split-K=6) -----
__global__ __launch_bounds__(256) void fproj_k(
    const f16* __restrict__ U16, const f16* __restrict__ F,
    float* __restrict__ fpart) {
  __shared__ f16 As[128 * 32];
  __shared__ f16 Bs[64 * 32];
  const int tid = threadIdx.x;
  const int lane = tid & 63;
  const int wave = tid >> 6;
  const int n0 = (int)blockIdx.x * 64;
  const int kc = (int)blockIdx.y;     // 0..5
  const int wm = (wave >> 1) * 64;
  const int wn = (wave & 1) * 32;
  const int fr = lane & 15;
  const int fq = lane >> 4;

  f32x4 acc[4][2];
#pragma unroll
  for (int i = 0; i < 4; i++)
#pragma unroll
    for (int j = 0; j < 2; j++) acc[i][j] = f32x4{0.f, 0.f, 0.f, 0.f};

  const int sr = lane >> 2;
  const int sc = (lane & 3) * 8;
  const f16* ag = U16 + (size_t)(wave * 32 + sr) * 2304 + kc * 384 + sc;
  const f16* bg = F + (size_t)(n0 + wave * 16 + sr) * 2304 + kc * 384 + sc;
  const size_t rstep = (size_t)16 * 2304;
  f16* la = As + wave * 32 * 32;
  f16* lb = Bs + wave * 16 * 32;

  for (int k0 = 0; k0 < 384; k0 += 32) {
    gload16(ag, la);  gload16(ag + rstep, la + 16 * 32);
    gload16(bg, lb);
    ag += 32; bg += 32;
    __syncthreads();
    f16x8 af[4], bf[2];
#pragma unroll
    for (int i = 0; i < 4; i++)
      af[i] = *(const f16x8*)&As[(wm + i * 16 + fr) * 32 + fq * 8];
#pragma unroll
    for (int j = 0; j < 2; j++)
      bf[j] = *(const f16x8*)&Bs[(wn + j * 16 + fr) * 32 + fq * 8];
#pragma unroll
    for (int i = 0; i < 4; i++)
#pragma unroll
      for (int j = 0; j < 2; j++)
        acc[i][j] = __builtin_amdgcn_mfma_f32_16x16x32_f16(af[i], bf[j], acc[i][j], 0, 0, 0);
    __syncthreads();
  }

#pragma unroll
  for (int i = 0; i < 4; i++)
#pragma unroll
    for (int j = 0; j < 2; j++)
#pragma unroll
      for (int rg = 0; rg < 4; rg++) {
        int gm = wm + i * 16 + fq * 4 + rg;
        int gn = n0 + wn + j * 16 + fr;
        fpart[((size_t)kc * 128 + gm) * EMB + gn] = acc[i][j][rg];
      }
}

// ---------------- combine fproj parts + bias2 + LN(ln1) + router top-2 ----------
__global__ __launch_bounds__(384) void ln_router_k(
    const float* __restrict__ fpart, const float* __restrict__ bias2,
    const float* __restrict__ g, const float* __restrict__ bb,
    const float* __restrict__ rw, const float* __restrict__ rb,
    f16* __restrict__ hcls16, float* __restrict__ maskw) {
  __shared__ float red[16];
  __shared__ float part[6][4];
  __shared__ float logits[4];
  int b = blockIdx.x, t = threadIdx.x;
  int lane = t & 63, wave = t >> 6;
  float v = bias2[t];
#pragma unroll
  for (int kc = 0; kc < 6; kc++)
    v += fpart[((size_t)kc * 128 + b) * EMB + t];
  float s = v, sq = v * v;
#pragma unroll
  for (int off = 32; off; off >>= 1) {
    s += __shfl_xor(s, off);
    sq += __shfl_xor(sq, off);
  }
  if (lane == 0) { red[wave] = s; red[8 + wave] = sq; }
  __syncthreads();
  float S = 0.f, SQ = 0.f;
#pragma unroll
  for (int i = 0; i < 6; i++) { S += red[i]; SQ += red[8 + i]; }
  float m = S * (1.f / 384.f);
  float rs = rsqrtf(SQ * (1.f / 384.f) - m * m + 1e-5f);
  float y = (v - m) * rs * g[t] + bb[t];
  hcls16[(size_t)b * EMB + t] = (f16)y;
  float p0 = y * rw[t];
  float p1 = y * rw[EMB + t];
  float p2 = y * rw[2 * EMB + t];
  float p3 = y * rw[3 * EMB + t];
#pragma unroll
  for (int off = 32; off; off >>= 1) {
    p0 += __shfl_xor(p0, off);
    p1 += __shfl_xor(p1, off);
    p2 += __shfl_xor(p2, off);
    p3 += __shfl_xor(p3, off);
  }
  if (lane == 0) { part[wave][0] = p0; part[wave][1] = p1; part[wave][2] = p2; part[wave][3] = p3; }
  __syncthreads();
  if (t < 4) {
    float a = rb[t];
#pragma unroll
    for (int i = 0; i < 6; i++) a += part[i][t];
    logits[t] = a;
  }
  __syncthreads();
  if (t == 0) {
    float l0 = logits[0], l1 = logits[1], l2 = logits[2], l3 = logits[3];
    int i1 = 0; float b1 = l0;
    if (l1 > b1) { b1 = l1; i1 = 1; }
    if (l2 > b1) { b1 = l2; i1 = 2; }
    if (l3 > b1) { b1 = l3; i1 = 3; }
    int i2 = -1; float b2 = 0.f;
    float lv[4] = {l0, l1, l2, l3};
#pragma unroll
    for (int i = 0; i < 4; i++) {
      if (i == i1) continue;
      if (i2 < 0 || lv[i] > b2) { i2 = i; b2 = lv[i]; }
    }
#pragma unroll
    for (int e = 0; e < 4; e++)
      maskw[(size_t)b * 4 + e] = (e == i1 || e == i2) ? 0.5f : 0.f;
  }
}

// ---------------- MoE GEMM1: hcls16[128x384] @ ew1t^T + GELU -> ehbuf f16 ---------
__global__ __launch_bounds__(256) void moe1_k(
    const f16* __restrict__ A, const f16* __restrict__ Bm,
    const float* __restrict__ bias, f16* __restrict__ outh) {
  __shared__ f16 As[128 * 32];
  __shared__ f16 Bs[64 * 32];
  const int K = EMB;
  const int tid = threadIdx.x;
  const int lane = tid & 63;
  const int wave = tid >> 6;
  const int e = (int)blockIdx.y;
  const int n0 = (int)blockIdx.x * 64;
  const int wm = (wave >> 1) * 64;
  const int wn = (wave & 1) * 32;
  const int fr = lane & 15;
  const int fq = lane >> 4;
  Bm += (size_t)e * HID * EMB;
  bias += (size_t)e * HID;

  f32x4 acc[4][2];
#pragma unroll
  for (int i = 0; i < 4; i++)
#pragma unroll
    for (int j = 0; j < 2; j++) acc[i][j] = f32x4{0.f, 0.f, 0.f, 0.f};

  const int sr = lane >> 2;
  const int sc = (lane & 3) * 8;
  const f16* ag = A + (size_t)(wave * 32 + sr) * K + sc;
  const f16* bg = Bm + (size_t)(n0 + wave * 16 + sr) * K + sc;
  const size_t rstep = (size_t)16 * K;
  f16* la = As + wave * 32 * 32;
  f16* lb = Bs + wave * 16 * 32;

  for (int k0 = 0; k0 < K; k0 += 32) {
    gload16(ag, la);  gload16(ag + rstep, la + 16 * 32);
    gload16(bg, lb);
    ag += 32; bg += 32;
    __syncthreads();
    f16x8 af[4], bf[2];
#pragma unroll
    for (int i = 0; i < 4; i++)
      af[i] = *(const f16x8*)&As[(wm + i * 16 + fr) * 32 + fq * 8];
#pragma unroll
    for (int j = 0; j < 2; j++)
      bf[j] = *(const f16x8*)&Bs[(wn + j * 16 + fr) * 32 + fq * 8];
#pragma unroll
    for (int i = 0; i < 4; i++)
#pragma unroll
      for (int j = 0; j < 2; j++)
        acc[i][j] = __builtin_amdgcn_mfma_f32_16x16x32_f16(af[i], bf[j], acc[i][j], 0, 0, 0);
    __syncthreads();
  }

#pragma unroll
  for (int i = 0; i < 4; i++)
#pragma unroll
    for (int j = 0; j < 2; j++)
#pragma unroll
      for (int rg = 0; rg < 4; rg++) {
        int gm = wm + i * 16 + fq * 4 + rg;
        int gn = n0 + wn + j * 16 + fr;
        float v = acc[i][j][rg] + bias[gn];
        float gl = 0.5f * v * (1.0f + erff(v * 0.70710678118654752f));
        outh[(size_t)e * 128 * HID + (size_t)gm * HID + gn] = (f16)gl;
      }
}

// ---------------- MoE GEMM2 split-K ----------------
__global__ __launch_bounds__(256) void moe2_k(
    const f16* __restrict__ EH, const f16* __restrict__ W2,
    float* __restrict__ part) {
  __shared__ f16 As[128 * 32];
  __shared__ f16 Bs[64 * 32];
  const int tid = threadIdx.x;
  const int lane = tid & 63;
  const int wave = tid >> 6;
  const int n0 = (int)blockIdx.x * 64;
  const int e = (int)blockIdx.y;
  const int kc = (int)blockIdx.z;
  const int wm = (wave >> 1) * 64;
  const int wn = (wave & 1) * 32;
  const int fr = lane & 15;
  const int fq = lane >> 4;
  const f16* A = EH + (size_t)e * 128 * HID + kc * 384;
  const f16* B = W2 + (size_t)e * EMB * HID + kc * 384;

  f32x4 acc[4][2];
#pragma unroll
  for (int i = 0; i < 4; i++)
#pragma unroll
    for (int j = 0; j < 2; j++) acc[i][j] = f32x4{0.f, 0.f, 0.f, 0.f};

  const int sr = lane >> 2;
  const int sc = (lane & 3) * 8;
  const f16* ag = A + (size_t)(wave * 32 + sr) * HID + sc;
  const f16* bg = B + (size_t)(n0 + wave * 16 + sr) * HID + sc;
  const size_t rstep = (size_t)16 * HID;
  f16* la = As + wave * 32 * 32;
  f16* lb = Bs + wave * 16 * 32;

  for (int k0 = 0; k0 < 384; k0 += 32) {
    gload16(ag, la);  gload16(ag + rstep, la + 16 * 32);
    gload16(bg, lb);
    ag += 32; bg += 32;
    __syncthreads();
    f16x8 af[4], bf[2];
#pragma unroll
    for (int i = 0; i < 4; i++)
      af[i] = *(const f16x8*)&As[(wm + i * 16 + fr) * 32 + fq * 8];
#pragma unroll
    for (int j = 0; j < 2; j++)
      bf[j] = *(const f16x8*)&Bs[(wn + j * 16 + fr) * 32 + fq * 8];
#pragma unroll
    for (int i = 0; i < 4; i++)
#pragma unroll
      for (int j = 0; j < 2; j++)
        acc[i][j] = __builtin_amdgcn_mfma_f32_16x16x32_f16(af[i], bf[j], acc[i][j], 0, 0, 0);
    __syncthreads();
  }

#pragma unroll
  for (int i = 0; i < 4; i++)
#pragma unroll
    for (int j = 0; j < 2; j++)
#pragma unroll
      for (int rg = 0; rg < 4; rg++) {
        int gm = wm + i * 16 + fq * 4 + rg;
        int gn = n0 + wn + j * 16 + fr;
        part[(((size_t)kc * 4 + e) * 128 + gm) * EMB + gn] = acc[i][j][rg];
      }
}

// ---------------- combine split-K + experts + LN2 -> f16 ----------------
__global__ __launch_bounds__(384) void combine_ln2_k(
    const float* __restrict__ part, const float* __restrict__ eb2,
    const float* __restrict__ maskw,
    const float* __restrict__ g, const float* __restrict__ bb,
    f16* __restrict__ hfin) {
  __shared__ float red[16];
  int b = blockIdx.x, t = threadIdx.x;
  int lane = t & 63, wave = t >> 6;
  float v = 0.f;
#pragma unroll
  for (int e = 0; e < 4; e++) {
    float s = eb2[e * EMB + t];
#pragma unroll
    for (int kc = 0; kc < 4; kc++)
      s += part[(((size_t)kc * 4 + e) * 128 + b) * EMB + t];
    v += maskw[b * 4 + e] * s;
  }
  float s = v, sq = v * v;
#pragma unroll
  for (int off = 32; off; off >>= 1) {
    s += __shfl_xor(s, off);
    sq += __shfl_xor(sq, off);
  }
  if (lane == 0) { red[wave] = s; red[8 + wave] = sq; }
  __syncthreads();
  float S = 0.f, SQ = 0.f;
#pragma unroll
  for (int i = 0; i < 6; i++) { S += red[i]; SQ += red[8 + i]; }
  float m = S * (1.f / 384.f);
  float rs = rsqrtf(SQ * (1.f / 384.f) - m * m + 1e-5f);
  hfin[(size_t)b * EMB + t] = (f16)((v - m) * rs * g[t] + bb[t]);
}

// ---------------- head GEMM (16 blocks, 128x64 tile) ----------------
__global__ __launch_bounds__(256) void head_gemm_k(
    const f16* __restrict__ A, const f16* __restrict__ B,
    const float* __restrict__ hb, float* __restrict__ outp) {
  __shared__ f16 As[128 * 32];
  __shared__ f16 Bs[64 * 32];
  const int K = 384;
  const int tid = threadIdx.x;
  const int lane = tid & 63;
  const int wave = tid >> 6;
  const int n0 = (int)blockIdx.x * 64;
  const int wm = (wave >> 1) * 64;
  const int wn = (wave & 1) * 32;
  const int fr = lane & 15;
  const int fq = lane >> 4;

  f32x4 acc[4][2];
#pragma unroll
  for (int i = 0; i < 4; i++)
#pragma unroll
    for (int j = 0; j < 2; j++) acc[i][j] = f32x4{0.f, 0.f, 0.f, 0.f};

  const int sr = lane >> 2;
  const int sc = (lane & 3) * 8;
  const f16* ag = A + (size_t)(wave * 32 + sr) * K + sc;
  const f16* bg = B + (size_t)(n0 + wave * 16 + sr) * K + sc;
  const size_t rstep = (size_t)16 * K;
  f16* la = As + wave * 32 * 32;
  f16* lb = Bs + wave * 16 * 32;

  for (int k0 = 0; k0 < K; k0 += 32) {
    gload16(ag, la);  gload16(ag + rstep, la + 16 * 32);
    gload16(bg, lb);
    ag += 32; bg += 32;
    __syncthreads();
    f16x8 af[4], bf[2];
#pragma unroll
    for (int i = 0; i < 4; i++)
      af[i] = *(const f16x8*)&As[(wm + i * 16 + fr) * 32 + fq * 8];
#pragma unroll
    for (int j = 0; j < 2; j++)
      bf[j] = *(const f16x8*)&Bs[(wn + j * 16 + fr) * 32 + fq * 8];
#pragma unroll
    for (int i = 0; i < 4; i++)
#pragma unroll
      for (int j = 0; j < 2; j++)
        acc[i][j] = __builtin_amdgcn_mfma_f32_16x16x32_f16(af[i], bf[j], acc[i][j], 0, 0, 0);
    __syncthreads();
  }

#pragma unroll
  for (int i = 0; i < 4; i++)
#pragma unroll
    for (int j = 0; j < 2; j++)
#pragma unroll
      for (int rg = 0; rg < 4; rg++) {
        int gm = wm + i * 16 + fq * 4 + rg;
        int gn = n0 + wn + j * 16 + fr;
        if (gn < 1000)
          outp[(size_t)gm * 1000 + gn] = acc[i][j][rg] + hb[gn];
      }
}

// ---------------- host ----------------
extern "C" void kernel_launch(void* const* d_in, const int* in_sizes, int n_in,
                              void* d_out, int out_size, void* d_ws, size_t ws_size,
                              hipStream_t stream) {
  const float* x      = (const float*)d_in[0];
  const float* conv_w = (const float*)d_in[1];
  const float* conv_b = (const float*)d_in[2];
  const float* cls_t  = (const float*)d_in[3];
  const float* pos    = (const float*)d_in[4];
  const float* ln1_g  = (const float*)d_in[5];
  const float* ln1_b  = (const float*)d_in[6];
  const float* inp_w  = (const float*)d_in[7];
  const float* inp_b  = (const float*)d_in[8];
  const float* outp_w = (const float*)d_in[9];
  const float* outp_b = (const float*)d_in[10];
  const float* rt_w   = (const float*)d_in[11];
  const float* rt_b   = (const float*)d_in[12];
  const float* ew1    = (const float*)d_in[13];
  const float* eb1    = (const float*)d_in[14];
  const float* ew2    = (const float*)d_in[15];
  const float* eb2    = (const float*)d_in[16];
  const float* ln2_g  = (const float*)d_in[17];
  const float* ln2_b  = (const float*)d_in[18];
  const float* head_w = (const float*)d_in[19];
  const float* head_b = (const float*)d_in[20];
  float* out = (float*)d_out;
  char* w = (char*)d_ws;
  if (ws_size < WS_NEEDED) return;

  f16* convw    = (f16*)(w + OFF_CONVW);
  f16* ew1t     = (f16*)(w + OFF_EW1T);
  f16* ew2t     = (f16*)(w + OFF_EW2T);
  f16* headw16  = (f16*)(w + OFF_HEADW16);
  f16* xcls16   = (f16*)(w + OFF_XCLS16);
  f16* hcls16   = (f16*)(w + OFF_HCLS16);
  float* maskw  = (float*)(w + OFF_MASKW);
  f16* ehbuf    = (f16*)(w + OFF_EH);
  float* epart  = (float*)(w + OFF_EPART);
  f16* hfin     = (f16*)(w + OFF_HFIN);
  f16* xh       = (f16*)(w + OFF_XH);
  float* Rg     = (float*)(w + OFF_R);
  float* Cg     = (float*)(w + OFF_CVEC);
  f16* u16      = (f16*)(w + OFF_U16);
  float* sg     = (float*)(w + OFF_SG);
  float* scls   = (float*)(w + OFF_SCLS);
  f16* Fw       = (f16*)(w + OFF_F);
  float* bias2  = (float*)(w + OFF_B2);
  float* fpart  = (float*)(w + OFF_FPART);

  // ---- all weight prep (casts + transposes + Wfused + bias2) in one launch ----
  prep_all_k<<<dim3(7464), 256, 0, stream>>>(
      conv_w, head_w, ew1, ew2, inp_w, inp_b, outp_w, outp_b,
      convw, headw16, ew1t, ew2t, Fw, bias2);

  // ---- cls LN + q/r/c/Scls precompute (one launch) ----
  clsrprep_k<<<dim3(6), 384, 0, stream>>>(
      cls_t, pos, ln1_g, ln1_b, inp_w, inp_b, xcls16, Rg, Cg, scls);

  // ---- fused implicit-im2col embed GEMM + LN1 + score epilogue + cls bcast ----
  embed_ln_k<<<dim3(392), 1024, 0, stream>>>(
      x, convw, conv_b, pos, ln1_g, ln1_b, Rg, Cg, xcls16, scls, xh, sg);

  // ---- softmax + u-GEMV -> U16 (512 thr, 8 token-slices) ----
  u_gemv_k<<<dim3(3, 128), 512, 0, stream>>>(sg, xh, u16);

  // ---- fused V+out projection (split-K=6) + combine/LN/router ----
  fproj_k<<<dim3(6, 6), 256, 0, stream>>>(u16, Fw, fpart);
  ln_router_k<<<dim3(128), 384, 0, stream>>>(
      fpart, bias2, ln1_g, ln1_b, rt_w, rt_b, hcls16, maskw);

  // ---- MoE ----
  moe1_k<<<dim3(24, 4), 256, 0, stream>>>(hcls16, ew1t, eb1, ehbuf);
  moe2_k<<<dim3(6, 4, 4), 256, 0, stream>>>(ehbuf, ew2t, epart);
  combine_ln2_k<<<dim3(128), 384, 0, stream>>>(epart, eb2, maskw, ln2_g, ln2_b, hfin);

  // ---- head (16 blocks) ----
  head_gemm_k<<<dim3(16), 256, 0, stream>>>(hfin, headw16, head_b, out);
  (void)in_sizes; (void)n_in; (void)out_size;
}